// Round 16
// baseline (1411.608 us; speedup 1.0000x reference)
//
#include <hip/hip_runtime.h>

// ---------------- problem constants ----------------
#define B_ 2
#define T_ 1024
#define C_ 768
#define H_ 12
#define L_ 6
#define V_ 32000
#define HS_ 64
#define M_ (B_*T_)            // 2048 token rows
#define C4_ (4*C_)            // 3072
#define NVC_ 6400             // lm_head column chunk (fallback path)

typedef __attribute__((ext_vector_type(8))) short short8;
typedef __attribute__((ext_vector_type(4))) float f32x4;

__device__ __forceinline__ float b2f(unsigned short u) {
  union { unsigned int i; float f; } x; x.i = ((unsigned int)u) << 16; return x.f;
}
__device__ __forceinline__ unsigned short f2b(float f) {
  unsigned int u = __builtin_bit_cast(unsigned int, f);
  u += 0x7fffu + ((u >> 16) & 1u);
  return (unsigned short)(u >> 16);
}

// async global->LDS, 16B per lane; LDS dest wave-uniform, lanes write dest + lane*16
__device__ __forceinline__ void gload16(const unsigned short* g, unsigned short* l) {
  __builtin_amdgcn_global_load_lds(
      (const __attribute__((address_space(1))) unsigned int*)g,
      (__attribute__((address_space(3))) unsigned int*)l, 16, 0, 0);
}

// -------- transpose + fp32->bf16: out[c][r] = bf16(in[r][c]), z-batched (VALIDATED) --------
__global__ __launch_bounds__(256) void transpose_f2b(const float* __restrict__ in,
                                                     unsigned short* __restrict__ out,
                                                     int ldi, int ldo, size_t zi, size_t zo) {
  __shared__ unsigned short tile[32][33];
  in  += zi * blockIdx.z;
  out += zo * blockIdx.z;
  int c0 = blockIdx.x * 32, r0 = blockIdx.y * 32;
  int tx = threadIdx.x & 31, ty = threadIdx.x >> 5;   // 32 x 8
  #pragma unroll
  for (int j = 0; j < 32; j += 8)
    tile[ty + j][tx] = f2b(in[(size_t)(r0 + ty + j) * ldi + c0 + tx]);
  __syncthreads();
  #pragma unroll
  for (int j = 0; j < 32; j += 8)
    out[(size_t)(c0 + ty + j) * ldo + r0 + tx] = tile[tx][ty + j];
}

// -------- merged QKV+P transpose: z in [0,48) --------
__global__ __launch_bounds__(256) void transpose_qkvp(const float* __restrict__ Wq,
                                                      const float* __restrict__ Wk,
                                                      const float* __restrict__ Wv,
                                                      const float* __restrict__ Wp,
                                                      unsigned short* __restrict__ out) {
  __shared__ unsigned short tile[32][33];
  int z = blockIdx.z;
  const float* in; unsigned short* o; int ldi; int cbase;
  if (z < 36) {
    int which = z / H_, hh = z % H_;
    in = (which == 0 ? Wq : which == 1 ? Wk : Wv) + (size_t)hh * C_ * HS_;
    o = out + (size_t)which * C_ * C_ + (size_t)hh * HS_ * C_;
    ldi = HS_; cbase = 0;
  } else {
    int ch = z - 36;
    in = Wp; ldi = C_; cbase = ch * 64;
    o = out + (size_t)3 * C_ * C_ + (size_t)ch * 64 * C_;
  }
  int c0 = blockIdx.x * 32, r0 = blockIdx.y * 32;
  int tx = threadIdx.x & 31, ty = threadIdx.x >> 5;
  #pragma unroll
  for (int j = 0; j < 32; j += 8)
    tile[ty + j][tx] = f2b(in[(size_t)(r0 + ty + j) * ldi + cbase + c0 + tx]);
  __syncthreads();
  #pragma unroll
  for (int j = 0; j < 32; j += 8)
    o[(size_t)(c0 + ty + j) * C_ + r0 + tx] = tile[tx][ty + j];
}

// ---------------- embedding ----------------
__global__ __launch_bounds__(256) void embed_kernel(const int* __restrict__ idx,
                                                    const float* __restrict__ tok,
                                                    const float* __restrict__ pos,
                                                    float* __restrict__ x) {
  int m = blockIdx.x;
  int t = m & (T_ - 1);
  int tk = idx[m];
  #pragma unroll
  for (int i = 0; i < 3; ++i) {
    int c = threadIdx.x + i * 256;
    x[(size_t)m * C_ + c] = tok[(size_t)tk * C_ + c] + pos[(size_t)t * C_ + c];
  }
}

// ---------------- layernorm: wave-per-row, no LDS, no barriers ----------------
__global__ __launch_bounds__(256) void ln_kernel(const float* __restrict__ x,
                                                 const float* __restrict__ g,
                                                 const float* __restrict__ bta,
                                                 unsigned short* __restrict__ h) {
  int wave = threadIdx.x >> 6, lane = threadIdx.x & 63;
  int m = blockIdx.x * 4 + wave;
  const float* xr = x + (size_t)m * C_;
  float v[12], s = 0.f, ss = 0.f;
  #pragma unroll
  for (int i = 0; i < 12; ++i) {
    v[i] = xr[lane + i * 64];
    s += v[i]; ss += v[i] * v[i];
  }
  #pragma unroll
  for (int off = 32; off; off >>= 1) { s += __shfl_xor(s, off); ss += __shfl_xor(ss, off); }
  float mean = s * (1.f / C_);
  float var  = fmaxf(ss * (1.f / C_) - mean * mean, 0.f);
  float rstd = rsqrtf(var + 1e-5f);
  #pragma unroll
  for (int i = 0; i < 12; ++i) {
    int c = lane + i * 64;
    h[(size_t)m * C_ + c] = f2b((v[i] - mean) * rstd * g[c] + bta[c]);
  }
}

// ---------------- MFMA flash attention (r12-validated math; 384 blocks, heavy-first) ----------------
__global__ __launch_bounds__(256) void attn_mfma(const unsigned short* __restrict__ q,
                                                 const unsigned short* __restrict__ k,
                                                 const unsigned short* __restrict__ v,
                                                 unsigned short* __restrict__ o) {
  const float scale = 0.03608439182435161f;   // 768^-0.5 (reference scales by C, not HS)
  __shared__ __align__(16) unsigned short Ks[64 * 72];
  __shared__ __align__(16) unsigned short Vt[64 * 72];
  __shared__ __align__(16) unsigned short Ps[4][16 * 72];

  int tid = threadIdx.x;
  int lane = tid & 63, wave = tid >> 6;
  int rl = lane & 15, kgrp = lane >> 4, koff = kgrp * 8;
  int qt = 15 - (int)blockIdx.x;         // heavy q-tiles dispatch first
  int bh = blockIdx.y;
  int hh = bh % H_, bb = bh / H_;
  size_t base = (size_t)bb * T_ * C_ + (size_t)hh * HS_;

  short8 qf0 = *(const short8*)&q[base + (size_t)(qt * 64 + wave * 16 + rl) * C_ + koff];
  short8 qf1 = *(const short8*)&q[base + (size_t)(qt * 64 + wave * 16 + rl) * C_ + 32 + koff];

  float m_[4], l_[4];
  f32x4 oacc[4];
  #pragma unroll
  for (int r = 0; r < 4; ++r) { m_[r] = -INFINITY; l_[r] = 0.f; }
  #pragma unroll
  for (int j = 0; j < 4; ++j) oacc[j] = (f32x4){0.f, 0.f, 0.f, 0.f};

  short8 kreg[2], vreg[2];
  #pragma unroll
  for (int i = 0; i < 2; ++i) {
    int e = tid + i * 256;
    kreg[i] = *(const short8*)&k[base + (size_t)(e >> 3) * C_ + (e & 7) * 8];
    vreg[i] = *(const short8*)&v[base + (size_t)(e >> 3) * C_ + (e & 7) * 8];
  }

  for (int kt = 0; kt <= qt; ++kt) {
    #pragma unroll
    for (int i = 0; i < 2; ++i) {
      int e = tid + i * 256, row = e >> 3, c8 = e & 7;
      *(short8*)&Ks[row * 72 + c8 * 8] = kreg[i];
    }
    #pragma unroll
    for (int i = 0; i < 2; ++i) {
      int e = tid + i * 256, kk = e >> 3, d8 = (e & 7) * 8;
      short8 vv = vreg[i];
      #pragma unroll
      for (int t2 = 0; t2 < 8; ++t2) {
        int ii = (t2 + tid) & 7;
        Vt[(d8 + ii) * 72 + kk] = vv[ii];
      }
    }
    __syncthreads();

    if (kt < qt) {
      #pragma unroll
      for (int i = 0; i < 2; ++i) {
        int e = tid + i * 256;
        kreg[i] = *(const short8*)&k[base + (size_t)((kt + 1) * 64 + (e >> 3)) * C_ + (e & 7) * 8];
        vreg[i] = *(const short8*)&v[base + (size_t)((kt + 1) * 64 + (e >> 3)) * C_ + (e & 7) * 8];
      }
    }

    f32x4 s[4];
    #pragma unroll
    for (int j = 0; j < 4; ++j) s[j] = (f32x4){0.f, 0.f, 0.f, 0.f};
    __builtin_amdgcn_s_setprio(1);
    #pragma unroll
    for (int j = 0; j < 4; ++j) {
      short8 b0 = *(const short8*)&Ks[(j * 16 + rl) * 72 + koff];
      short8 b1 = *(const short8*)&Ks[(j * 16 + rl) * 72 + 32 + koff];
      s[j] = __builtin_amdgcn_mfma_f32_16x16x32_bf16(qf0, b0, s[j], 0, 0, 0);
      s[j] = __builtin_amdgcn_mfma_f32_16x16x32_bf16(qf1, b1, s[j], 0, 0, 0);
    }
    __builtin_amdgcn_s_setprio(0);

    bool diag = (kt == qt);
    #pragma unroll
    for (int j = 0; j < 4; ++j)
      #pragma unroll
      for (int r = 0; r < 4; ++r) {
        float sv = s[j][r] * scale;
        if (diag) {
          int urow = j * 16 + rl, qrow = wave * 16 + kgrp * 4 + r;
          if (urow > qrow) sv = -INFINITY;
        }
        s[j][r] = sv;
      }

    float corr[4], rs[4];
    #pragma unroll
    for (int r = 0; r < 4; ++r) {
      float mrow = fmaxf(fmaxf(s[0][r], s[1][r]), fmaxf(s[2][r], s[3][r]));
      #pragma unroll
      for (int off = 8; off; off >>= 1) mrow = fmaxf(mrow, __shfl_xor(mrow, off));
      float mnew = fmaxf(m_[r], mrow);
      corr[r] = __expf(m_[r] - mnew);
      m_[r] = mnew;
    }
    #pragma unroll
    for (int r = 0; r < 4; ++r) rs[r] = 0.f;
    #pragma unroll
    for (int j = 0; j < 4; ++j)
      #pragma unroll
      for (int r = 0; r < 4; ++r) {
        float p = (s[j][r] == -INFINITY) ? 0.f : __expf(s[j][r] - m_[r]);
        s[j][r] = p;
        rs[r] += p;
      }
    #pragma unroll
    for (int r = 0; r < 4; ++r) {
      #pragma unroll
      for (int off = 8; off; off >>= 1) rs[r] += __shfl_xor(rs[r], off);
      l_[r] = l_[r] * corr[r] + rs[r];
    }
    #pragma unroll
    for (int j = 0; j < 4; ++j)
      #pragma unroll
      for (int r = 0; r < 4; ++r) oacc[j][r] *= corr[r];

    #pragma unroll
    for (int j = 0; j < 4; ++j)
      #pragma unroll
      for (int r = 0; r < 4; ++r)
        Ps[wave][(kgrp * 4 + r) * 72 + j * 16 + rl] = f2b(s[j][r]);

    short8 pa0 = *(const short8*)&Ps[wave][rl * 72 + koff];
    short8 pa1 = *(const short8*)&Ps[wave][rl * 72 + 32 + koff];
    __builtin_amdgcn_s_setprio(1);
    #pragma unroll
    for (int j = 0; j < 4; ++j) {
      short8 b0 = *(const short8*)&Vt[(j * 16 + rl) * 72 + koff];
      short8 b1 = *(const short8*)&Vt[(j * 16 + rl) * 72 + 32 + koff];
      oacc[j] = __builtin_amdgcn_mfma_f32_16x16x32_bf16(pa0, b0, oacc[j], 0, 0, 0);
      oacc[j] = __builtin_amdgcn_mfma_f32_16x16x32_bf16(pa1, b1, oacc[j], 0, 0, 0);
    }
    __builtin_amdgcn_s_setprio(0);
    __syncthreads();
  }

  #pragma unroll
  for (int j = 0; j < 4; ++j)
    #pragma unroll
    for (int r = 0; r < 4; ++r) {
      int qrow = wave * 16 + kgrp * 4 + r;
      o[base + (size_t)(qt * 64 + qrow) * C_ + j * 16 + rl] = f2b(oacc[j][r] / l_[r]);
    }
}

// ------- MFMA BT GEMM: BK=64, zero-conflict XOR swizzle, single-buffer (r14-validated) -------
// Wave tile = (BM/2)x(BN/2); BM=128/BN=256 gives FN=8 (25% less LDS traffic per FLOP).
// MFAST: m-tile fastest. SWZ: bijective XCD remap (m204). EPI: 0 bf16, 1 relu bf16, 2 f32 +=, 3 f32
template<int BM, int BN, int EPI, bool MFAST, bool SWZ>
__global__ __launch_bounds__(256) void gemm_bt(const unsigned short* __restrict__ A,
                                               const unsigned short* __restrict__ Bt,
                                               const float* __restrict__ bias,
                                               unsigned short* __restrict__ outb,
                                               float* __restrict__ outf,
                                               int M, int N, int K, int ldO,
                                               size_t zBt, size_t zOut, int nMt) {
  constexpr int BK = 64;
  __shared__ __align__(16) unsigned short As[BM * BK];
  __shared__ __align__(16) unsigned short Bs[BN * BK];
  constexpr int FM = BM / 32, FN = BN / 32;

  int tid = threadIdx.x;
  int lane = tid & 63, wave = tid >> 6;
  int wr = wave >> 1, wc = wave & 1;
  int m0, n0;
  if (SWZ) {
    int nwg = gridDim.x, wg = blockIdx.x;
    int qq = nwg >> 3, rr = nwg & 7;
    int xcd = wg & 7, off = wg >> 3;
    int wgid = (xcd < rr ? xcd * (qq + 1) : rr * (qq + 1) + (xcd - rr) * qq) + off;
    m0 = (wgid % nMt) * BM;
    n0 = (wgid / nMt) * BN;
  } else {
    m0 = (MFAST ? blockIdx.x : blockIdx.y) * BM;
    n0 = (MFAST ? blockIdx.y : blockIdx.x) * BN;
  }
  int rl = lane & 15, kgrp = lane >> 4;
  Bt += zBt * blockIdx.z;

  // staging: one gload16 covers 8 rows of 128B; lane l -> row l>>3, global chunk (l&7)^(l>>3)
  int srow = lane >> 3;
  int scol = ((lane & 7) ^ srow) * 8;

  // read-side physical chunk offsets (elems) for k-low / k-high halves
  int pc0 = ((kgrp)     ^ (rl & 7)) * 8;
  int pc1 = ((4 + kgrp) ^ (rl & 7)) * 8;

  f32x4 acc[FM][FN] = {};

  for (int k0 = 0; k0 < K; k0 += BK) {
    #pragma unroll
    for (int i = 0; i < BM / 32; ++i) {
      int r = i * 32 + wave * 8;             // multiple of 8 (wave-uniform)
      gload16(&A[(size_t)(m0 + r + srow) * K + k0 + scol], &As[r * BK]);
    }
    #pragma unroll
    for (int i = 0; i < BN / 32; ++i) {
      int r = i * 32 + wave * 8;
      gload16(&Bt[(size_t)(n0 + r + srow) * K + k0 + scol], &Bs[r * BK]);
    }
    __syncthreads();   // compiler drains vmcnt before barrier

    short8 af0[FM], af1[FM], bf0[FN], bf1[FN];
    #pragma unroll
    for (int i = 0; i < FM; ++i) {
      int row = wr * (BM / 2) + i * 16 + rl;
      af0[i] = *(const short8*)&As[row * BK + pc0];
      af1[i] = *(const short8*)&As[row * BK + pc1];
    }
    #pragma unroll
    for (int j = 0; j < FN; ++j) {
      int row = wc * (BN / 2) + j * 16 + rl;
      bf0[j] = *(const short8*)&Bs[row * BK + pc0];
      bf1[j] = *(const short8*)&Bs[row * BK + pc1];
    }
    __builtin_amdgcn_s_setprio(1);
    #pragma unroll
    for (int i = 0; i < FM; ++i)
      #pragma unroll
      for (int j = 0; j < FN; ++j) {
        acc[i][j] = __builtin_amdgcn_mfma_f32_16x16x32_bf16(af0[i], bf0[j], acc[i][j], 0, 0, 0);
        acc[i][j] = __builtin_amdgcn_mfma_f32_16x16x32_bf16(af1[i], bf1[j], acc[i][j], 0, 0, 0);
      }
    __builtin_amdgcn_s_setprio(0);
    __syncthreads();
  }

  int rbase = kgrp * 4;
  #pragma unroll
  for (int i = 0; i < FM; ++i) {
    #pragma unroll
    for (int j = 0; j < FN; ++j) {
      #pragma unroll
      for (int r = 0; r < 4; ++r) {
        int m = m0 + wr * (BM / 2) + i * 16 + rbase + r;
        int n = n0 + wc * (BN / 2) + j * 16 + rl;
        float val = acc[i][j][r];
        if (bias) val += bias[n];
        if (EPI == 0)      (outb + zOut * blockIdx.z)[(size_t)m * ldO + n] = f2b(val);
        else if (EPI == 1) (outb + zOut * blockIdx.z)[(size_t)m * ldO + n] = f2b(fmaxf(val, 0.f));
        else if (EPI == 2) (outf + zOut * blockIdx.z)[(size_t)m * ldO + n] += val;
        else               (outf + zOut * blockIdx.z)[(size_t)m * ldO + n] = val;
      }
    }
  }
}

// ---------------- host-side launch ----------------
extern "C" void kernel_launch(void* const* d_in, const int* in_sizes, int n_in,
                              void* d_out, int out_size, void* d_ws, size_t ws_size,
                              hipStream_t stream) {
  const int*   idx  = (const int*)d_in[0];
  const float* tok  = (const float*)d_in[1];
  const float* pos  = (const float*)d_in[2];
  const float* Wq   = (const float*)d_in[3];
  const float* Wk   = (const float*)d_in[4];
  const float* Wv   = (const float*)d_in[5];
  const float* Wp   = (const float*)d_in[6];
  const float* bp   = (const float*)d_in[7];
  const float* ln1g = (const float*)d_in[8];
  const float* ln1b = (const float*)d_in[9];
  const float* ln2g = (const float*)d_in[10];
  const float* ln2b = (const float*)d_in[11];
  const float* W1   = (const float*)d_in[12];
  const float* b1   = (const float*)d_in[13];
  const float* W2   = (const float*)d_in[14];
  const float* b2   = (const float*)d_in[15];
  const float* lnfg = (const float*)d_in[16];
  const float* lnfb = (const float*)d_in[17];
  const float* Wh   = (const float*)d_in[18];
  const float* bh   = (const float*)d_in[19];

  float* out = (float*)d_out;   // fp32 logits

  const size_t MC = (size_t)M_ * C_;
  const size_t fixed = MC*4 + MC*2 + MC*2*4;                 // x, h, qkvo region
  const size_t need_chunk = fixed + (size_t)NVC_*C_*2;       // 31.9 MB (proven available)
  const size_t need_full  = fixed + (size_t)V_*C_*2;         // 71.2 MB (runtime-checked)
  if (ws_size < need_chunk) return;
  const bool full_head = (ws_size >= need_full);

  char* p = (char*)d_ws;
  float*          x   = (float*)p;            p += MC*4;
  unsigned short* h   = (unsigned short*)p;   p += MC*2;
  unsigned short* qb  = (unsigned short*)p;   p += MC*2;   // qb,kb,vb contiguous (z-batch)
  unsigned short* kb  = (unsigned short*)p;   p += MC*2;
  unsigned short* vb  = (unsigned short*)p;   p += MC*2;
  unsigned short* ob  = (unsigned short*)p;   p += MC*2;
  unsigned short* WT  = (unsigned short*)p;                // 9.8 MB (chunk) or 49 MB (full)
  unsigned short* mid = qb;                   // [M][C4] bf16, overlays qkvo (dead)

  unsigned short* WqT = WT;                   // WqT,WkT,WvT,WpT contiguous
  unsigned short* WpT = WT + (size_t)3*C_*C_;
  unsigned short* W12T = WT;

  embed_kernel<<<M_, 256, 0, stream>>>(idx, tok, pos, x);

  for (int l = 0; l < L_; ++l) {
    size_t wo  = (size_t)l * C_ * C_;
    size_t wo4 = (size_t)l * C_ * C4_;
    size_t woq = (size_t)l * H_ * C_ * HS_;

    transpose_qkvp<<<dim3(HS_/32, C_/32, 48), 256, 0, stream>>>(Wq + woq, Wk + woq, Wv + woq, Wp + wo, WqT);

    ln_kernel<<<M_/4, 256, 0, stream>>>(x, ln1g + (size_t)l*C_, ln1b + (size_t)l*C_, h);
    gemm_bt<64,64,0,false,false><<<dim3(C_/64, M_/64, 3), 256, 0, stream>>>(h, WqT, nullptr, qb, nullptr,
                                                                            M_, C_, C_, C_, (size_t)C_*C_, MC, 0);
    attn_mfma<<<dim3(16, B_*H_), 256, 0, stream>>>(qb, kb, vb, ob);
    gemm_bt<64,64,2,false,false><<<dim3(C_/64, M_/64), 256, 0, stream>>>(ob, WpT, bp + (size_t)l*C_, nullptr, x,
                                                                         M_, C_, C_, C_, 0, 0, 0);

    ln_kernel<<<M_/4, 256, 0, stream>>>(x, ln2g + (size_t)l*C_, ln2b + (size_t)l*C_, h);
    transpose_f2b<<<dim3(C4_/32, C_/32, 1), 256, 0, stream>>>(W1 + wo4, W12T, C4_, C_, 0, 0);
    gemm_bt<128,128,1,true,true><<<dim3((M_/128)*(C4_/128)), 256, 0, stream>>>(h, W12T, b1 + (size_t)l*C4_, mid, nullptr,
                                                                               M_, C4_, C_, C4_, 0, 0, M_/128);
    transpose_f2b<<<dim3(C_/32, C4_/32, 1), 256, 0, stream>>>(W2 + wo4, W12T, C_, C4_, 0, 0);
    gemm_bt<64,64,2,true,true><<<dim3((M_/64)*(C_/64)), 256, 0, stream>>>(mid, W12T, b2 + (size_t)l*C_, nullptr, x,
                                                                          M_, C_, C4_, C_, 0, 0, M_/64);
  }

  // ---- final LN + lm_head (fp32 store); 128x256 tile (FN=8) for lower LDS traffic ----
  ln_kernel<<<M_/4, 256, 0, stream>>>(x, lnfg, lnfb, h);
  if (full_head) {
    transpose_f2b<<<dim3(V_/32, C_/32, 1), 256, 0, stream>>>(Wh, WT, V_, C_, 0, 0);
    gemm_bt<128,256,3,true,true><<<dim3((M_/128)*(V_/256)), 256, 0, stream>>>(
        h, WT, bh, nullptr, out, M_, V_, C_, V_, 0, 0, M_/128);
  } else {
    for (int ci = 0; ci < V_/NVC_; ++ci) {
      transpose_f2b<<<dim3(NVC_/32, C_/32, 1), 256, 0, stream>>>(Wh + (size_t)ci*NVC_, WT, V_, C_, 0, 0);
      gemm_bt<128,256,3,true,true><<<dim3((M_/128)*(NVC_/256)), 256, 0, stream>>>(
          h, WT, bh + (size_t)ci*NVC_, nullptr, out + (size_t)ci*NVC_, M_, NVC_, C_, V_, 0, 0, M_/128);
    }
  }
}

// Round 17
// 1186.249 us; speedup vs baseline: 1.1900x; 1.1900x over previous
//
#include <hip/hip_runtime.h>

// ---------------- problem constants ----------------
#define B_ 2
#define T_ 1024
#define C_ 768
#define H_ 12
#define L_ 6
#define V_ 32000
#define HS_ 64
#define M_ (B_*T_)            // 2048 token rows
#define C4_ (4*C_)            // 3072
#define NVC_ 6400             // lm_head column chunk (fallback path)

typedef __attribute__((ext_vector_type(8))) short short8;
typedef __attribute__((ext_vector_type(4))) float f32x4;

__device__ __forceinline__ float b2f(unsigned short u) {
  union { unsigned int i; float f; } x; x.i = ((unsigned int)u) << 16; return x.f;
}
__device__ __forceinline__ unsigned short f2b(float f) {
  unsigned int u = __builtin_bit_cast(unsigned int, f);
  u += 0x7fffu + ((u >> 16) & 1u);
  return (unsigned short)(u >> 16);
}

// async global->LDS, 16B per lane; LDS dest wave-uniform, lanes write dest + lane*16
__device__ __forceinline__ void gload16(const unsigned short* g, unsigned short* l) {
  __builtin_amdgcn_global_load_lds(
      (const __attribute__((address_space(1))) unsigned int*)g,
      (__attribute__((address_space(3))) unsigned int*)l, 16, 0, 0);
}

// -------- transpose + fp32->bf16: out[c][r] = bf16(in[r][c]), z-batched (VALIDATED) --------
__global__ __launch_bounds__(256) void transpose_f2b(const float* __restrict__ in,
                                                     unsigned short* __restrict__ out,
                                                     int ldi, int ldo, size_t zi, size_t zo) {
  __shared__ unsigned short tile[32][33];
  in  += zi * blockIdx.z;
  out += zo * blockIdx.z;
  int c0 = blockIdx.x * 32, r0 = blockIdx.y * 32;
  int tx = threadIdx.x & 31, ty = threadIdx.x >> 5;   // 32 x 8
  #pragma unroll
  for (int j = 0; j < 32; j += 8)
    tile[ty + j][tx] = f2b(in[(size_t)(r0 + ty + j) * ldi + c0 + tx]);
  __syncthreads();
  #pragma unroll
  for (int j = 0; j < 32; j += 8)
    out[(size_t)(c0 + ty + j) * ldo + r0 + tx] = tile[tx][ty + j];
}

// -------- merged QKV+P transpose: z in [0,48) --------
__global__ __launch_bounds__(256) void transpose_qkvp(const float* __restrict__ Wq,
                                                      const float* __restrict__ Wk,
                                                      const float* __restrict__ Wv,
                                                      const float* __restrict__ Wp,
                                                      unsigned short* __restrict__ out) {
  __shared__ unsigned short tile[32][33];
  int z = blockIdx.z;
  const float* in; unsigned short* o; int ldi; int cbase;
  if (z < 36) {
    int which = z / H_, hh = z % H_;
    in = (which == 0 ? Wq : which == 1 ? Wk : Wv) + (size_t)hh * C_ * HS_;
    o = out + (size_t)which * C_ * C_ + (size_t)hh * HS_ * C_;
    ldi = HS_; cbase = 0;
  } else {
    int ch = z - 36;
    in = Wp; ldi = C_; cbase = ch * 64;
    o = out + (size_t)3 * C_ * C_ + (size_t)ch * 64 * C_;
  }
  int c0 = blockIdx.x * 32, r0 = blockIdx.y * 32;
  int tx = threadIdx.x & 31, ty = threadIdx.x >> 5;
  #pragma unroll
  for (int j = 0; j < 32; j += 8)
    tile[ty + j][tx] = f2b(in[(size_t)(r0 + ty + j) * ldi + cbase + c0 + tx]);
  __syncthreads();
  #pragma unroll
  for (int j = 0; j < 32; j += 8)
    o[(size_t)(c0 + ty + j) * C_ + r0 + tx] = tile[tx][ty + j];
}

// ---------------- embedding ----------------
__global__ __launch_bounds__(256) void embed_kernel(const int* __restrict__ idx,
                                                    const float* __restrict__ tok,
                                                    const float* __restrict__ pos,
                                                    float* __restrict__ x) {
  int m = blockIdx.x;
  int t = m & (T_ - 1);
  int tk = idx[m];
  #pragma unroll
  for (int i = 0; i < 3; ++i) {
    int c = threadIdx.x + i * 256;
    x[(size_t)m * C_ + c] = tok[(size_t)tk * C_ + c] + pos[(size_t)t * C_ + c];
  }
}

// ---------------- layernorm: wave-per-row, no LDS, no barriers ----------------
__global__ __launch_bounds__(256) void ln_kernel(const float* __restrict__ x,
                                                 const float* __restrict__ g,
                                                 const float* __restrict__ bta,
                                                 unsigned short* __restrict__ h) {
  int wave = threadIdx.x >> 6, lane = threadIdx.x & 63;
  int m = blockIdx.x * 4 + wave;
  const float* xr = x + (size_t)m * C_;
  float v[12], s = 0.f, ss = 0.f;
  #pragma unroll
  for (int i = 0; i < 12; ++i) {
    v[i] = xr[lane + i * 64];
    s += v[i]; ss += v[i] * v[i];
  }
  #pragma unroll
  for (int off = 32; off; off >>= 1) { s += __shfl_xor(s, off); ss += __shfl_xor(ss, off); }
  float mean = s * (1.f / C_);
  float var  = fmaxf(ss * (1.f / C_) - mean * mean, 0.f);
  float rstd = rsqrtf(var + 1e-5f);
  #pragma unroll
  for (int i = 0; i < 12; ++i) {
    int c = lane + i * 64;
    h[(size_t)m * C_ + c] = f2b((v[i] - mean) * rstd * g[c] + bta[c]);
  }
}

// ---------------- MFMA flash attention (r14-proven: paired q-tiles, 2 passes) ----------------
__global__ __launch_bounds__(256) void attn_mfma(const unsigned short* __restrict__ q,
                                                 const unsigned short* __restrict__ k,
                                                 const unsigned short* __restrict__ v,
                                                 unsigned short* __restrict__ o) {
  const float scale = 0.03608439182435161f;   // 768^-0.5 (reference scales by C, not HS)
  __shared__ __align__(16) unsigned short Ks[64 * 72];
  __shared__ __align__(16) unsigned short Vt[64 * 72];
  __shared__ __align__(16) unsigned short Ps[4][16 * 72];

  int tid = threadIdx.x;
  int lane = tid & 63, wave = tid >> 6;
  int rl = lane & 15, kgrp = lane >> 4, koff = kgrp * 8;
  int bh = blockIdx.y;
  int hh = bh % H_, bb = bh / H_;
  size_t base = (size_t)bb * T_ * C_ + (size_t)hh * HS_;

  for (int pass = 0; pass < 2; ++pass) {
    int qt = pass ? (15 - (int)blockIdx.x) : (int)blockIdx.x;

    short8 qf0 = *(const short8*)&q[base + (size_t)(qt * 64 + wave * 16 + rl) * C_ + koff];
    short8 qf1 = *(const short8*)&q[base + (size_t)(qt * 64 + wave * 16 + rl) * C_ + 32 + koff];

    float m_[4], l_[4];
    f32x4 oacc[4];
    #pragma unroll
    for (int r = 0; r < 4; ++r) { m_[r] = -INFINITY; l_[r] = 0.f; }
    #pragma unroll
    for (int j = 0; j < 4; ++j) oacc[j] = (f32x4){0.f, 0.f, 0.f, 0.f};

    short8 kreg[2], vreg[2];
    #pragma unroll
    for (int i = 0; i < 2; ++i) {
      int e = tid + i * 256;
      kreg[i] = *(const short8*)&k[base + (size_t)(e >> 3) * C_ + (e & 7) * 8];
      vreg[i] = *(const short8*)&v[base + (size_t)(e >> 3) * C_ + (e & 7) * 8];
    }

    for (int kt = 0; kt <= qt; ++kt) {
      #pragma unroll
      for (int i = 0; i < 2; ++i) {
        int e = tid + i * 256, row = e >> 3, c8 = e & 7;
        *(short8*)&Ks[row * 72 + c8 * 8] = kreg[i];
      }
      #pragma unroll
      for (int i = 0; i < 2; ++i) {
        int e = tid + i * 256, kk = e >> 3, d8 = (e & 7) * 8;
        short8 vv = vreg[i];
        #pragma unroll
        for (int t2 = 0; t2 < 8; ++t2) {
          int ii = (t2 + tid) & 7;
          Vt[(d8 + ii) * 72 + kk] = vv[ii];
        }
      }
      __syncthreads();

      if (kt < qt) {
        #pragma unroll
        for (int i = 0; i < 2; ++i) {
          int e = tid + i * 256;
          kreg[i] = *(const short8*)&k[base + (size_t)((kt + 1) * 64 + (e >> 3)) * C_ + (e & 7) * 8];
          vreg[i] = *(const short8*)&v[base + (size_t)((kt + 1) * 64 + (e >> 3)) * C_ + (e & 7) * 8];
        }
      }

      f32x4 s[4];
      #pragma unroll
      for (int j = 0; j < 4; ++j) s[j] = (f32x4){0.f, 0.f, 0.f, 0.f};
      __builtin_amdgcn_s_setprio(1);
      #pragma unroll
      for (int j = 0; j < 4; ++j) {
        short8 b0 = *(const short8*)&Ks[(j * 16 + rl) * 72 + koff];
        short8 b1 = *(const short8*)&Ks[(j * 16 + rl) * 72 + 32 + koff];
        s[j] = __builtin_amdgcn_mfma_f32_16x16x32_bf16(qf0, b0, s[j], 0, 0, 0);
        s[j] = __builtin_amdgcn_mfma_f32_16x16x32_bf16(qf1, b1, s[j], 0, 0, 0);
      }
      __builtin_amdgcn_s_setprio(0);

      bool diag = (kt == qt);
      #pragma unroll
      for (int j = 0; j < 4; ++j)
        #pragma unroll
        for (int r = 0; r < 4; ++r) {
          float sv = s[j][r] * scale;
          if (diag) {
            int urow = j * 16 + rl, qrow = wave * 16 + kgrp * 4 + r;
            if (urow > qrow) sv = -INFINITY;
          }
          s[j][r] = sv;
        }

      float corr[4], rs[4];
      #pragma unroll
      for (int r = 0; r < 4; ++r) {
        float mrow = fmaxf(fmaxf(s[0][r], s[1][r]), fmaxf(s[2][r], s[3][r]));
        #pragma unroll
        for (int off = 8; off; off >>= 1) mrow = fmaxf(mrow, __shfl_xor(mrow, off));
        float mnew = fmaxf(m_[r], mrow);
        corr[r] = __expf(m_[r] - mnew);
        m_[r] = mnew;
      }
      #pragma unroll
      for (int r = 0; r < 4; ++r) rs[r] = 0.f;
      #pragma unroll
      for (int j = 0; j < 4; ++j)
        #pragma unroll
        for (int r = 0; r < 4; ++r) {
          float p = (s[j][r] == -INFINITY) ? 0.f : __expf(s[j][r] - m_[r]);
          s[j][r] = p;
          rs[r] += p;
        }
      #pragma unroll
      for (int r = 0; r < 4; ++r) {
        #pragma unroll
        for (int off = 8; off; off >>= 1) rs[r] += __shfl_xor(rs[r], off);
        l_[r] = l_[r] * corr[r] + rs[r];
      }
      #pragma unroll
      for (int j = 0; j < 4; ++j)
        #pragma unroll
        for (int r = 0; r < 4; ++r) oacc[j][r] *= corr[r];

      #pragma unroll
      for (int j = 0; j < 4; ++j)
        #pragma unroll
        for (int r = 0; r < 4; ++r)
          Ps[wave][(kgrp * 4 + r) * 72 + j * 16 + rl] = f2b(s[j][r]);

      short8 pa0 = *(const short8*)&Ps[wave][rl * 72 + koff];
      short8 pa1 = *(const short8*)&Ps[wave][rl * 72 + 32 + koff];
      __builtin_amdgcn_s_setprio(1);
      #pragma unroll
      for (int j = 0; j < 4; ++j) {
        short8 b0 = *(const short8*)&Vt[(j * 16 + rl) * 72 + koff];
        short8 b1 = *(const short8*)&Vt[(j * 16 + rl) * 72 + 32 + koff];
        oacc[j] = __builtin_amdgcn_mfma_f32_16x16x32_bf16(pa0, b0, oacc[j], 0, 0, 0);
        oacc[j] = __builtin_amdgcn_mfma_f32_16x16x32_bf16(pa1, b1, oacc[j], 0, 0, 0);
      }
      __builtin_amdgcn_s_setprio(0);
      __syncthreads();
    }

    #pragma unroll
    for (int j = 0; j < 4; ++j)
      #pragma unroll
      for (int r = 0; r < 4; ++r) {
        int qrow = wave * 16 + kgrp * 4 + r;
        o[base + (size_t)(qt * 64 + qrow) * C_ + j * 16 + rl] = f2b(oacc[j][r] / l_[r]);
      }
  }
}

// ------- MFMA BT GEMM: BK=64, zero-conflict XOR swizzle, single-buffer (r14-PROVEN) -------
// MFAST: m-tile fastest. SWZ: bijective XCD remap (m204). EPI: 0 bf16, 1 relu bf16, 2 f32 +=, 3 f32
template<int BM, int BN, int EPI, bool MFAST, bool SWZ>
__global__ __launch_bounds__(256) void gemm_bt(const unsigned short* __restrict__ A,
                                               const unsigned short* __restrict__ Bt,
                                               const float* __restrict__ bias,
                                               unsigned short* __restrict__ outb,
                                               float* __restrict__ outf,
                                               int M, int N, int K, int ldO,
                                               size_t zBt, size_t zOut, int nMt) {
  constexpr int BK = 64;
  __shared__ __align__(16) unsigned short As[BM * BK];
  __shared__ __align__(16) unsigned short Bs[BN * BK];
  constexpr int FM = BM / 32, FN = BN / 32;

  int tid = threadIdx.x;
  int lane = tid & 63, wave = tid >> 6;
  int wr = wave >> 1, wc = wave & 1;
  int m0, n0;
  if (SWZ) {
    int nwg = gridDim.x, wg = blockIdx.x;
    int qq = nwg >> 3, rr = nwg & 7;
    int xcd = wg & 7, off = wg >> 3;
    int wgid = (xcd < rr ? xcd * (qq + 1) : rr * (qq + 1) + (xcd - rr) * qq) + off;
    m0 = (wgid % nMt) * BM;
    n0 = (wgid / nMt) * BN;
  } else {
    m0 = (MFAST ? blockIdx.x : blockIdx.y) * BM;
    n0 = (MFAST ? blockIdx.y : blockIdx.x) * BN;
  }
  int rl = lane & 15, kgrp = lane >> 4;
  Bt += zBt * blockIdx.z;

  int srow = lane >> 3;
  int scol = ((lane & 7) ^ srow) * 8;
  int pc0 = ((kgrp)     ^ (rl & 7)) * 8;
  int pc1 = ((4 + kgrp) ^ (rl & 7)) * 8;

  f32x4 acc[FM][FN] = {};

  for (int k0 = 0; k0 < K; k0 += BK) {
    #pragma unroll
    for (int i = 0; i < BM / 32; ++i) {
      int r = i * 32 + wave * 8;
      gload16(&A[(size_t)(m0 + r + srow) * K + k0 + scol], &As[r * BK]);
    }
    #pragma unroll
    for (int i = 0; i < BN / 32; ++i) {
      int r = i * 32 + wave * 8;
      gload16(&Bt[(size_t)(n0 + r + srow) * K + k0 + scol], &Bs[r * BK]);
    }
    __syncthreads();

    short8 af0[FM], af1[FM], bf0[FN], bf1[FN];
    #pragma unroll
    for (int i = 0; i < FM; ++i) {
      int row = wr * (BM / 2) + i * 16 + rl;
      af0[i] = *(const short8*)&As[row * BK + pc0];
      af1[i] = *(const short8*)&As[row * BK + pc1];
    }
    #pragma unroll
    for (int j = 0; j < FN; ++j) {
      int row = wc * (BN / 2) + j * 16 + rl;
      bf0[j] = *(const short8*)&Bs[row * BK + pc0];
      bf1[j] = *(const short8*)&Bs[row * BK + pc1];
    }
    __builtin_amdgcn_s_setprio(1);
    #pragma unroll
    for (int i = 0; i < FM; ++i)
      #pragma unroll
      for (int j = 0; j < FN; ++j) {
        acc[i][j] = __builtin_amdgcn_mfma_f32_16x16x32_bf16(af0[i], bf0[j], acc[i][j], 0, 0, 0);
        acc[i][j] = __builtin_amdgcn_mfma_f32_16x16x32_bf16(af1[i], bf1[j], acc[i][j], 0, 0, 0);
      }
    __builtin_amdgcn_s_setprio(0);
    __syncthreads();
  }

  int rbase = kgrp * 4;
  #pragma unroll
  for (int i = 0; i < FM; ++i) {
    #pragma unroll
    for (int j = 0; j < FN; ++j) {
      #pragma unroll
      for (int r = 0; r < 4; ++r) {
        int m = m0 + wr * (BM / 2) + i * 16 + rbase + r;
        int n = n0 + wc * (BN / 2) + j * 16 + rl;
        float val = acc[i][j][r];
        if (bias) val += bias[n];
        if (EPI == 0)      (outb + zOut * blockIdx.z)[(size_t)m * ldO + n] = f2b(val);
        else if (EPI == 1) (outb + zOut * blockIdx.z)[(size_t)m * ldO + n] = f2b(fmaxf(val, 0.f));
        else if (EPI == 2) (outf + zOut * blockIdx.z)[(size_t)m * ldO + n] += val;
        else               (outf + zOut * blockIdx.z)[(size_t)m * ldO + n] = val;
      }
    }
  }
}

// ------- 256x256-tile 8-wave GEMM for the lm_head (fp32 out + bias) -------
// Same validated staging/swizzle/fragment algebra; wave grid 2x4, per-wave 128x64 output.
// k-low then k-high per acc element (same per-element order -> bit-identical).
__global__ __launch_bounds__(512) void gemm_bt256(const unsigned short* __restrict__ A,
                                                  const unsigned short* __restrict__ Bt,
                                                  const float* __restrict__ bias,
                                                  float* __restrict__ outf,
                                                  int M, int N, int K, int ldO, int nMt) {
  constexpr int BK = 64;
  __shared__ __align__(16) unsigned short As[256 * BK];
  __shared__ __align__(16) unsigned short Bs[256 * BK];

  int tid = threadIdx.x;
  int lane = tid & 63, wave = tid >> 6;       // 8 waves
  int wr = wave >> 2, wc = wave & 3;          // 2 x 4
  int nwg = gridDim.x, wg = blockIdx.x;       // bijective XCD remap, m fastest
  int qq = nwg >> 3, rr = nwg & 7;
  int xcd = wg & 7, off = wg >> 3;
  int wgid = (xcd < rr ? xcd * (qq + 1) : rr * (qq + 1) + (xcd - rr) * qq) + off;
  int m0 = (wgid % nMt) * 256;
  int n0 = (wgid / nMt) * 256;
  int rl = lane & 15, kgrp = lane >> 4;

  int srow = lane >> 3;
  int scol = ((lane & 7) ^ srow) * 8;
  int pc0 = ((kgrp)     ^ (rl & 7)) * 8;
  int pc1 = ((4 + kgrp) ^ (rl & 7)) * 8;

  f32x4 acc[8][4] = {};

  for (int k0 = 0; k0 < K; k0 += BK) {
    #pragma unroll
    for (int i = 0; i < 4; ++i) {
      int r = wave * 32 + i * 8;              // 8 rows per gload16
      gload16(&A[(size_t)(m0 + r + srow) * K + k0 + scol], &As[r * BK]);
      gload16(&Bt[(size_t)(n0 + r + srow) * K + k0 + scol], &Bs[r * BK]);
    }
    __syncthreads();

    {   // k-low half
      short8 af[8], bf[4];
      #pragma unroll
      for (int i = 0; i < 8; ++i) af[i] = *(const short8*)&As[(wr * 128 + i * 16 + rl) * BK + pc0];
      #pragma unroll
      for (int j = 0; j < 4; ++j) bf[j] = *(const short8*)&Bs[(wc * 64 + j * 16 + rl) * BK + pc0];
      __builtin_amdgcn_s_setprio(1);
      #pragma unroll
      for (int i = 0; i < 8; ++i)
        #pragma unroll
        for (int j = 0; j < 4; ++j)
          acc[i][j] = __builtin_amdgcn_mfma_f32_16x16x32_bf16(af[i], bf[j], acc[i][j], 0, 0, 0);
      __builtin_amdgcn_s_setprio(0);
    }
    {   // k-high half
      short8 af[8], bf[4];
      #pragma unroll
      for (int i = 0; i < 8; ++i) af[i] = *(const short8*)&As[(wr * 128 + i * 16 + rl) * BK + pc1];
      #pragma unroll
      for (int j = 0; j < 4; ++j) bf[j] = *(const short8*)&Bs[(wc * 64 + j * 16 + rl) * BK + pc1];
      __builtin_amdgcn_s_setprio(1);
      #pragma unroll
      for (int i = 0; i < 8; ++i)
        #pragma unroll
        for (int j = 0; j < 4; ++j)
          acc[i][j] = __builtin_amdgcn_mfma_f32_16x16x32_bf16(af[i], bf[j], acc[i][j], 0, 0, 0);
      __builtin_amdgcn_s_setprio(0);
    }
    __syncthreads();
  }

  int rbase = kgrp * 4;
  #pragma unroll
  for (int i = 0; i < 8; ++i) {
    #pragma unroll
    for (int j = 0; j < 4; ++j) {
      #pragma unroll
      for (int r = 0; r < 4; ++r) {
        int m = m0 + wr * 128 + i * 16 + rbase + r;
        int n = n0 + wc * 64 + j * 16 + rl;
        outf[(size_t)m * ldO + n] = acc[i][j][r] + bias[n];
      }
    }
  }
}

// ---------------- host-side launch ----------------
extern "C" void kernel_launch(void* const* d_in, const int* in_sizes, int n_in,
                              void* d_out, int out_size, void* d_ws, size_t ws_size,
                              hipStream_t stream) {
  const int*   idx  = (const int*)d_in[0];
  const float* tok  = (const float*)d_in[1];
  const float* pos  = (const float*)d_in[2];
  const float* Wq   = (const float*)d_in[3];
  const float* Wk   = (const float*)d_in[4];
  const float* Wv   = (const float*)d_in[5];
  const float* Wp   = (const float*)d_in[6];
  const float* bp   = (const float*)d_in[7];
  const float* ln1g = (const float*)d_in[8];
  const float* ln1b = (const float*)d_in[9];
  const float* ln2g = (const float*)d_in[10];
  const float* ln2b = (const float*)d_in[11];
  const float* W1   = (const float*)d_in[12];
  const float* b1   = (const float*)d_in[13];
  const float* W2   = (const float*)d_in[14];
  const float* b2   = (const float*)d_in[15];
  const float* lnfg = (const float*)d_in[16];
  const float* lnfb = (const float*)d_in[17];
  const float* Wh   = (const float*)d_in[18];
  const float* bh   = (const float*)d_in[19];

  float* out = (float*)d_out;   // fp32 logits

  const size_t MC = (size_t)M_ * C_;
  const size_t fixed = MC*4 + MC*2 + MC*2*4;                 // x, h, qkvo region
  const size_t need_chunk = fixed + (size_t)NVC_*C_*2;       // 31.9 MB (proven available)
  const size_t need_full  = fixed + (size_t)V_*C_*2;         // 71.2 MB (runtime-checked)
  if (ws_size < need_chunk) return;
  const bool full_head = (ws_size >= need_full);

  char* p = (char*)d_ws;
  float*          x   = (float*)p;            p += MC*4;
  unsigned short* h   = (unsigned short*)p;   p += MC*2;
  unsigned short* qb  = (unsigned short*)p;   p += MC*2;   // qb,kb,vb contiguous (z-batch)
  unsigned short* kb  = (unsigned short*)p;   p += MC*2;
  unsigned short* vb  = (unsigned short*)p;   p += MC*2;
  unsigned short* ob  = (unsigned short*)p;   p += MC*2;
  unsigned short* WT  = (unsigned short*)p;                // 9.8 MB (chunk) or 49 MB (full)
  unsigned short* mid = qb;                   // [M][C4] bf16, overlays qkvo (dead)

  unsigned short* WqT = WT;                   // WqT,WkT,WvT,WpT contiguous
  unsigned short* WpT = WT + (size_t)3*C_*C_;
  unsigned short* W12T = WT;

  embed_kernel<<<M_, 256, 0, stream>>>(idx, tok, pos, x);

  for (int l = 0; l < L_; ++l) {
    size_t wo  = (size_t)l * C_ * C_;
    size_t wo4 = (size_t)l * C_ * C4_;
    size_t woq = (size_t)l * H_ * C_ * HS_;

    transpose_qkvp<<<dim3(HS_/32, C_/32, 48), 256, 0, stream>>>(Wq + woq, Wk + woq, Wv + woq, Wp + wo, WqT);

    ln_kernel<<<M_/4, 256, 0, stream>>>(x, ln1g + (size_t)l*C_, ln1b + (size_t)l*C_, h);
    gemm_bt<64,64,0,false,false><<<dim3(C_/64, M_/64, 3), 256, 0, stream>>>(h, WqT, nullptr, qb, nullptr,
                                                                            M_, C_, C_, C_, (size_t)C_*C_, MC, 0);
    attn_mfma<<<dim3(8, B_*H_), 256, 0, stream>>>(qb, kb, vb, ob);
    gemm_bt<64,64,2,false,false><<<dim3(C_/64, M_/64), 256, 0, stream>>>(ob, WpT, bp + (size_t)l*C_, nullptr, x,
                                                                         M_, C_, C_, C_, 0, 0, 0);

    ln_kernel<<<M_/4, 256, 0, stream>>>(x, ln2g + (size_t)l*C_, ln2b + (size_t)l*C_, h);
    transpose_f2b<<<dim3(C4_/32, C_/32, 1), 256, 0, stream>>>(W1 + wo4, W12T, C4_, C_, 0, 0);
    gemm_bt<128,128,1,true,true><<<dim3((M_/128)*(C4_/128)), 256, 0, stream>>>(h, W12T, b1 + (size_t)l*C4_, mid, nullptr,
                                                                               M_, C4_, C_, C4_, 0, 0, M_/128);
    transpose_f2b<<<dim3(C_/32, C4_/32, 1), 256, 0, stream>>>(W2 + wo4, W12T, C_, C4_, 0, 0);
    gemm_bt<64,64,2,true,true><<<dim3((M_/64)*(C_/64)), 256, 0, stream>>>(mid, W12T, b2 + (size_t)l*C_, nullptr, x,
                                                                          M_, C_, C4_, C_, 0, 0, M_/64);
  }

  // ---- final LN + lm_head (fp32 store); 256^2 8-wave tile ----
  ln_kernel<<<M_/4, 256, 0, stream>>>(x, lnfg, lnfb, h);
  if (full_head) {
    transpose_f2b<<<dim3(V_/32, C_/32, 1), 256, 0, stream>>>(Wh, WT, V_, C_, 0, 0);
    gemm_bt256<<<dim3((M_/256)*(V_/256)), 512, 0, stream>>>(
        h, WT, bh, out, M_, V_, C_, V_, M_/256);
  } else {
    for (int ci = 0; ci < V_/NVC_; ++ci) {
      transpose_f2b<<<dim3(NVC_/32, C_/32, 1), 256, 0, stream>>>(Wh + (size_t)ci*NVC_, WT, V_, C_, 0, 0);
      gemm_bt<128,128,3,true,true><<<dim3((M_/128)*(NVC_/128)), 256, 0, stream>>>(
          h, WT, bh + (size_t)ci*NVC_, nullptr, out + (size_t)ci*NVC_, M_, NVC_, C_, V_, 0, 0, M_/128);
    }
  }
}